// Round 10
// baseline (167.226 us; speedup 1.0000x reference)
//
#include <hip/hip_runtime.h>
#include <hip/hip_bf16.h>

typedef __bf16 bf16_t;
typedef __attribute__((ext_vector_type(8))) __bf16 bf16x8;
typedef __attribute__((ext_vector_type(4))) __bf16 bf16x4;
typedef __attribute__((ext_vector_type(4))) float f32x4;
typedef __attribute__((ext_vector_type(16))) float f32x16;
typedef __attribute__((ext_vector_type(2))) int i32x2;

#define B_ 2
#define T_ 2048
#define D_ 1024
#define H_ 16
#define DH_ 64
#define RS_ 3072  // fused qkv row stride

static __device__ __forceinline__ f32x4 mfma16(bf16x8 a, bf16x8 b, f32x4 c) {
  return __builtin_amdgcn_mfma_f32_16x16x32_bf16(a, b, c, 0, 0, 0);
}
static __device__ __forceinline__ f32x16 mfma32(bf16x8 a, bf16x8 b, f32x16 c) {
  return __builtin_amdgcn_mfma_f32_32x32x16_bf16(a, b, c, 0, 0, 0);
}
static __device__ __forceinline__ void gld16(const bf16_t* g, bf16_t* l) {
  __builtin_amdgcn_global_load_lds(
      (const __attribute__((address_space(1))) unsigned int*)g,
      (__attribute__((address_space(3))) unsigned int*)l, 16, 0, 0);
}
static __device__ __forceinline__ unsigned lds_addr(const bf16_t* p) {
  return (unsigned)(uintptr_t)(const __attribute__((address_space(3))) bf16_t*)p;
}
static __device__ __forceinline__ i32x2 tr64(unsigned a) {
  i32x2 d;
  asm volatile("ds_read_b64_tr_b16 %0, %1" : "=v"(d) : "v"(a));
  return d;
}
static __device__ __forceinline__ i32x2 tr64o(unsigned a) {  // +128B (4 k-rows)
  i32x2 d;
  asm volatile("ds_read_b64_tr_b16 %0, %1 offset:128" : "=v"(d) : "v"(a));
  return d;
}
static __device__ __forceinline__ unsigned pk2(float lo, float hi2) {
  unsigned short a = __builtin_bit_cast(unsigned short, (bf16_t)lo);
  unsigned short b = __builtin_bit_cast(unsigned short, (bf16_t)hi2);
  return (unsigned)a | ((unsigned)b << 16);
}

#define WAITV4 { asm volatile("s_waitcnt vmcnt(4)" ::: "memory"); __builtin_amdgcn_sched_barrier(0); }
#define WAITV0 { asm volatile("s_waitcnt vmcnt(0)" ::: "memory"); __builtin_amdgcn_sched_barrier(0); }
#define BAR    { __builtin_amdgcn_s_barrier(); __builtin_amdgcn_sched_barrier(0); }
#define WAITL0 { asm volatile("s_waitcnt lgkmcnt(0)" ::: "memory"); __builtin_amdgcn_sched_barrier(0); }

// ---------------- fp32 -> bf16 conversion ----------------
__global__ __launch_bounds__(256) void cvt_x(const float* __restrict__ in,
                                             bf16_t* __restrict__ out, int n4) {
  int i = blockIdx.x * 256 + threadIdx.x;
  if (i >= n4) return;
  float4 f = reinterpret_cast<const float4*>(in)[i];
  bf16x4 o;
  o[0] = (bf16_t)f.x; o[1] = (bf16_t)f.y; o[2] = (bf16_t)f.z; o[3] = (bf16_t)f.w;
  reinterpret_cast<bf16x4*>(out)[i] = o;
}

__global__ __launch_bounds__(256) void cvt_w4(const float* __restrict__ w0,
                                              const float* __restrict__ w1,
                                              const float* __restrict__ w2,
                                              const float* __restrict__ w3,
                                              bf16_t* __restrict__ out, int n4each) {
  const float* in = blockIdx.y == 0 ? w0 : blockIdx.y == 1 ? w1 : blockIdx.y == 2 ? w2 : w3;
  bf16_t* o = out + (size_t)blockIdx.y * (size_t)n4each * 4;
  int i = blockIdx.x * 256 + threadIdx.x;
  if (i >= n4each) return;
  float4 f = reinterpret_cast<const float4*>(in)[i];
  bf16x4 v;
  v[0] = (bf16_t)f.x; v[1] = (bf16_t)f.y; v[2] = (bf16_t)f.z; v[3] = (bf16_t)f.w;
  reinterpret_cast<bf16x4*>(o)[i] = v;
}

// ---------------- NT GEMM: C = A * B^T (unchanged from R7) ----------------
template <bool STORE_F32, bool QSCALE>
__global__ __launch_bounds__(256) void gemm_nt(const bf16_t* __restrict__ A,
                                               const bf16_t* __restrict__ Bm,
                                               void* __restrict__ Cv,
                                               int M, int N, int K) {
  __shared__ __align__(16) bf16_t As[3][128 * 32];
  __shared__ __align__(16) bf16_t Bs[3][128 * 32];
  const int tid = threadIdx.x, lane = tid & 63, wave = tid >> 6;
  const int l15 = lane & 15;
  const int brow = blockIdx.y * 128, bcol = blockIdx.x * 128;
  const int row0 = (wave >> 1) * 64, col0 = (wave & 1) * 64;
  const float cscale = (QSCALE && bcol < 1024) ? 0.18033688011112042f : 1.0f;

  f32x4 acc[4][4];
#pragma unroll
  for (int m = 0; m < 4; ++m)
#pragma unroll
    for (int n = 0; n < 4; ++n) acc[m][n] = f32x4{0.f, 0.f, 0.f, 0.f};

  const int nst = K >> 5;
  const int srow = tid >> 2;
  const int sc8 = (tid & 3) * 8;
  auto stage = [&](int bi, int ks) {
    const int k0 = ks * 32;
#pragma unroll
    for (int i = 0; i < 2; ++i)
      gld16(A + (size_t)(brow + 64 * i + srow) * K + k0 + sc8,
            &As[bi][2048 * i + 512 * wave]);
#pragma unroll
    for (int i = 0; i < 2; ++i)
      gld16(Bm + (size_t)(bcol + 64 * i + srow) * K + k0 + sc8,
            &Bs[bi][2048 * i + 512 * wave]);
  };

  stage(0, 0);
  stage(1, 1);

#pragma unroll 1
  for (int ks = 0; ks < nst; ++ks) {
    if (ks + 1 < nst) { WAITV4 } else { WAITV0 }
    BAR;
    if (ks + 2 < nst) stage((ks + 2) % 3, ks + 2);

    const bf16_t* Ab = &As[ks % 3][0];
    const bf16_t* Bb = &Bs[ks % 3][0];
    const int ko = (lane >> 4) * 8;
    bf16x8 af[4], bfr[4];
#pragma unroll
    for (int m = 0; m < 4; ++m)
      af[m] = *(const bf16x8*)&Ab[(row0 + 16 * m + l15) * 32 + ko];
#pragma unroll
    for (int n = 0; n < 4; ++n)
      bfr[n] = *(const bf16x8*)&Bb[(col0 + 16 * n + l15) * 32 + ko];
    WAITL0;
#pragma unroll
    for (int m = 0; m < 4; ++m)
#pragma unroll
      for (int n = 0; n < 4; ++n) acc[m][n] = mfma16(af[m], bfr[n], acc[m][n]);
  }

  const int crow = brow + row0 + (lane >> 4) * 4;
  const int ccol = bcol + col0 + l15;
#pragma unroll
  for (int m = 0; m < 4; ++m)
#pragma unroll
    for (int n = 0; n < 4; ++n)
#pragma unroll
      for (int r = 0; r < 4; ++r) {
        size_t idx = (size_t)(crow + 16 * m + r) * N + (ccol + 16 * n);
        float v = acc[m][n][r] * cscale;
        if (STORE_F32) reinterpret_cast<float*>(Cv)[idx] = v;
        else reinterpret_cast<bf16_t*>(Cv)[idx] = (bf16_t)v;
      }
}

// ---------------- causal flash attention: k-split + flash-merge ----------------
// grid (32 bh, 16 a), 256 thr = 4 waves = 2 chunks (ci) x 2 key-parity splits (ks).
//   phase A: chunks {a, 63-a};  phase B: {31-a, 32+a}  -> all 64 chunks once.
//   Block stage total = 49 tiles for EVERY a -> all 512 blocks identical -> flat
//   2 blocks/CU (LDS 65KB, VGPR capped 128) = 8 waves/CU.
// Wave (ci,ks) computes tiles kt with kt&1==ks against private (m,l,o); partial
// states merged at phase end via LDS scratch (standard flash merge, exp2 domain).
#define CROW(r) ((((r) & 3) + 8 * ((r) >> 2)) + 4 * hi)

__global__ __launch_bounds__(256, 2) void attn_fwd(const bf16_t* __restrict__ qkv,
                                                   bf16_t* __restrict__ ctx) {
  __shared__ __align__(128) bf16_t KV[3][2][4096];   // staging: 48 KB
  __shared__ float sc_o[2][2][16][64];               // [ci][n2][r][lane]: 16 KB
  __shared__ float sc_ml[2][2][32];                  // [ci][m|l][q]
  const int tid = threadIdx.x;
  const int lane = tid & 63;
  const int wv = tid >> 6;
  const int ci = wv & 1, ks = wv >> 1;
  const int bh = blockIdx.x, a = blockIdx.y;
  const int b = bh >> 4, h = bh & 15;
  const bf16_t* Qg = qkv + (size_t)b * T_ * RS_ + h * DH_;
  const bf16_t* Kg = Qg + 1024;
  const bf16_t* Vg = Qg + 2048;
  bf16_t* Cg = ctx + (size_t)b * T_ * D_ + h * DH_;

  const int hi = lane >> 5;
  const int l31 = lane & 31;
  const int l15 = lane & 15;

  // cooperative staging of one 64-key tile (identical to R6)
  auto stage = [&](int bi, int kt) {
    bf16_t* Kb = &KV[bi][0][0];
    bf16_t* Vb = &KV[bi][1][0];
#pragma unroll
    for (int i = 0; i < 2; ++i) {
      int c2 = i * 256 + tid;
      int r = c2 >> 3, g8 = (c2 & 7) ^ (r & 7);
      gld16(Kg + (size_t)(kt * 64 + r) * RS_ + g8 * 8, Kb + i * 2048 + wv * 512);
    }
#pragma unroll
    for (int i = 0; i < 2; ++i) {
      int c2 = i * 256 + tid;
      int pn = c2 >> 7, k = (c2 >> 1) & 63, half = c2 & 1;
      gld16(Vg + (size_t)(kt * 64 + k) * RS_ + pn * 16 + half * 8, Vb + i * 2048 + wv * 512);
    }
  };

#pragma unroll 1
  for (int phase = 0; phase < 2; ++phase) {
    const int c = phase ? (ci ? 32 + a : 31 - a) : (ci ? 63 - a : a);
    const int q0 = c * 32;
    const int nkt = (c >> 1) + 1;                                 // my chunk's tiles
    const int maxnkt = phase ? (((32 + a) >> 1) + 1) : (((63 - a) >> 1) + 1);  // staged

    BAR;  // previous phase fully done (incl. merge reads) before re-staging
    stage(0, 0);
    stage(1, 1);

    bf16x8 qf[4];
#pragma unroll
    for (int d = 0; d < 4; ++d)
      qf[d] = *(const bf16x8*)&Qg[(size_t)(q0 + l31) * RS_ + d * 16 + hi * 8];

    f32x16 o[2];
#pragma unroll
    for (int n = 0; n < 2; ++n)
#pragma unroll
      for (int r = 0; r < 16; ++r) o[n][r] = 0.f;
    float mrow = -1e30f, lsum = 0.f;

#pragma unroll 1
    for (int kt = 0; kt < maxnkt; ++kt) {
      if (kt + 1 < maxnkt) { WAITV4 } else { WAITV0 }
      BAR;
      if (kt + 2 < maxnkt) stage((kt + 2) % 3, kt + 2);

      if (((kt & 1) == ks) && kt < nkt) {
        const bf16_t* Kb = &KV[kt % 3][0][0];
        bf16x8 kf[2][4];
#pragma unroll
        for (int t = 0; t < 2; ++t)
#pragma unroll
          for (int d = 0; d < 4; ++d) {
            int row = 32 * t + l31;
            int col = ((d * 2 + hi) ^ (row & 7)) * 8;
            kf[t][d] = *(const bf16x8*)&Kb[row * 64 + col];
          }
        bf16x8 vf[2][4];
        {
          unsigned vb = lds_addr(&KV[kt % 3][1][0]);
#pragma unroll
          for (int n2 = 0; n2 < 2; ++n2)
#pragma unroll
            for (int kss = 0; kss < 4; ++kss) {
              int pn = 2 * n2 + (l31 >> 4);
              int k0 = kss * 16 + hi * 8;
              unsigned ad = vb + pn * 2048 + k0 * 32 + l15 * 8;
              i32x2 lo = tr64(ad);
              i32x2 hi4 = tr64o(ad);
              union { unsigned u[4]; bf16x8 v; } uu;
              uu.u[0] = (unsigned)lo[0]; uu.u[1] = (unsigned)lo[1];
              uu.u[2] = (unsigned)hi4[0]; uu.u[3] = (unsigned)hi4[1];
              vf[n2][kss] = uu.v;
            }
        }
        WAITL0;

        f32x16 st[2];
#pragma unroll
        for (int t = 0; t < 2; ++t) {
#pragma unroll
          for (int r = 0; r < 16; ++r) st[t][r] = 0.f;
#pragma unroll
          for (int d = 0; d < 4; ++d) st[t] = mfma32(kf[t][d], qf[d], st[t]);
        }
        if (kt == nkt - 1) {  // diagonal tile (its parity wave only)
#pragma unroll
          for (int t = 0; t < 2; ++t)
#pragma unroll
            for (int r = 0; r < 16; ++r)
              if (kt * 64 + 32 * t + CROW(r) > q0 + l31) st[t][r] = -1e30f;
        }
        float pm = -1e30f;
#pragma unroll
        for (int t = 0; t < 2; ++t)
#pragma unroll
          for (int r = 0; r < 16; ++r) pm = fmaxf(pm, st[t][r]);
        pm = fmaxf(pm, __shfl_xor(pm, 32));
        if (!__all(pm - mrow <= 11.0f)) {  // defer-max
          float mn = fmaxf(mrow, pm);
          float scl = exp2f(mrow - mn);
          mrow = mn;
          lsum *= scl;
#pragma unroll
          for (int r = 0; r < 16; ++r) {
            float sr = __shfl(scl, CROW(r));
            o[0][r] *= sr;
            o[1][r] *= sr;
          }
        }
        float ps = 0.f;
#pragma unroll
        for (int t = 0; t < 2; ++t)
#pragma unroll
          for (int r = 0; r < 16; ++r) {
            float e = exp2f(st[t][r] - mrow);
            st[t][r] = e;
            ps += e;
          }
        ps += __shfl_xor(ps, 32);
        lsum += ps;
        unsigned pk[2][8];
#pragma unroll
        for (int t = 0; t < 2; ++t)
#pragma unroll
          for (int j = 0; j < 8; ++j) pk[t][j] = pk2(st[t][2 * j], st[t][2 * j + 1]);
#pragma unroll
        for (int kss = 0; kss < 4; ++kss) {
          const int t = kss >> 1, rb = (kss & 1) * 4;
          unsigned s0 = hi ? pk[t][rb] : pk[t][rb + 2];
          unsigned s1 = hi ? pk[t][rb + 1] : pk[t][rb + 3];
          unsigned r0 = (unsigned)__shfl_xor((int)s0, 32);
          unsigned r1 = (unsigned)__shfl_xor((int)s1, 32);
          union { unsigned u[4]; bf16x8 v; } w;
          if (hi == 0) {
            w.u[0] = pk[t][rb]; w.u[1] = pk[t][rb + 1]; w.u[2] = r0; w.u[3] = r1;
          } else {
            w.u[0] = r0; w.u[1] = r1; w.u[2] = pk[t][rb + 2]; w.u[3] = pk[t][rb + 3];
          }
          o[0] = mfma32(w.v, vf[0][kss], o[0]);
          o[1] = mfma32(w.v, vf[1][kss], o[1]);
        }
      }  // parity/guard
    }  // kt

    // ---- flash merge of the two parity partials, then write ----
    BAR;  // all compute done
    if (ks == 1) {
      if (hi == 0) {
        sc_ml[ci][0][l31] = mrow;
        sc_ml[ci][1][l31] = lsum;
      }
#pragma unroll
      for (int n2 = 0; n2 < 2; ++n2)
#pragma unroll
        for (int r = 0; r < 16; ++r) sc_o[ci][n2][r][lane] = o[n2][r];
    }
    BAR;
    if (ks == 0) {
      float m1q = sc_ml[ci][0][l31];
      float l1q = sc_ml[ci][1][l31];
      float mn = fmaxf(mrow, m1q);
      float s0 = exp2f(mrow - mn);
      float s1 = exp2f(m1q - mn);
      float lf = lsum * s0 + l1q * s1;
#pragma unroll
      for (int r = 0; r < 16; ++r) {
        float s0r = __shfl(s0, CROW(r));
        float s1r = __shfl(s1, CROW(r));
        float li = __shfl(lf, CROW(r));
        float inv = 1.0f / li;
        int qrow = q0 + CROW(r);
#pragma unroll
        for (int n2 = 0; n2 < 2; ++n2) {
          float of = o[n2][r] * s0r + sc_o[ci][n2][r][lane] * s1r;
          Cg[(size_t)qrow * D_ + n2 * 32 + l31] = (bf16_t)(of * inv);
        }
      }
    }
  }  // phase
}

// ---------------- launch ----------------
extern "C" void kernel_launch(void* const* d_in, const int* in_sizes, int n_in,
                              void* d_out, int out_size, void* d_ws, size_t ws_size,
                              hipStream_t stream) {
  const float* x   = (const float*)d_in[0];
  const float* w_q = (const float*)d_in[1];
  const float* w_k = (const float*)d_in[2];
  const float* w_v = (const float*)d_in[3];
  const float* w_o = (const float*)d_in[4];

  const int M = B_ * T_;              // 4096
  const size_t XN = (size_t)M * D_;   // 4M
  const size_t WN = (size_t)D_ * D_;  // 1M

  bf16_t* ws = (bf16_t*)d_ws;
  bf16_t* xb   = ws;            // 4M
  bf16_t* wqb  = xb + XN;       // 3M (q,k,v) + 1M (o) contiguous
  bf16_t* wob  = wqb + 3 * WN;
  bf16_t* qkv  = wob + WN;      // [4096][3072] = 12M
  bf16_t* ctx  = qkv + (size_t)M * RS_;  // 4M

  cvt_x<<<(int)(XN / 4 / 256), 256, 0, stream>>>(x, xb, (int)(XN / 4));
  cvt_w4<<<dim3((int)(WN / 4 / 256), 4), 256, 0, stream>>>(w_q, w_k, w_v, w_o, wqb, (int)(WN / 4));

  // fused QKV GEMM: B = [w_q; w_k; w_v] (3072 x 1024), q-part pre-scaled (exp2 domain)
  gemm_nt<false, true><<<dim3(RS_ / 128, M / 128), 256, 0, stream>>>(xb, wqb, qkv, M, RS_, D_);

  attn_fwd<<<dim3(B_ * H_, 16), 256, 0, stream>>>(qkv, ctx);

  gemm_nt<true, false><<<dim3(D_ / 128, M / 128), 256, 0, stream>>>(ctx, wob, d_out, M, D_, D_);
}

// Round 11
// 153.801 us; speedup vs baseline: 1.0873x; 1.0873x over previous
//
#include <hip/hip_runtime.h>
#include <hip/hip_bf16.h>

typedef __bf16 bf16_t;
typedef __attribute__((ext_vector_type(8))) __bf16 bf16x8;
typedef __attribute__((ext_vector_type(4))) __bf16 bf16x4;
typedef __attribute__((ext_vector_type(4))) float f32x4;
typedef __attribute__((ext_vector_type(16))) float f32x16;
typedef __attribute__((ext_vector_type(2))) int i32x2;

#define B_ 2
#define T_ 2048
#define D_ 1024
#define H_ 16
#define DH_ 64
#define RS_ 3072  // fused qkv row stride

static __device__ __forceinline__ f32x4 mfma16(bf16x8 a, bf16x8 b, f32x4 c) {
  return __builtin_amdgcn_mfma_f32_16x16x32_bf16(a, b, c, 0, 0, 0);
}
static __device__ __forceinline__ f32x16 mfma32(bf16x8 a, bf16x8 b, f32x16 c) {
  return __builtin_amdgcn_mfma_f32_32x32x16_bf16(a, b, c, 0, 0, 0);
}
static __device__ __forceinline__ void gld16(const bf16_t* g, bf16_t* l) {
  __builtin_amdgcn_global_load_lds(
      (const __attribute__((address_space(1))) unsigned int*)g,
      (__attribute__((address_space(3))) unsigned int*)l, 16, 0, 0);
}
static __device__ __forceinline__ unsigned lds_addr(const bf16_t* p) {
  return (unsigned)(uintptr_t)(const __attribute__((address_space(3))) bf16_t*)p;
}
static __device__ __forceinline__ i32x2 tr64(unsigned a) {
  i32x2 d;
  asm volatile("ds_read_b64_tr_b16 %0, %1" : "=v"(d) : "v"(a));
  return d;
}
static __device__ __forceinline__ i32x2 tr64o(unsigned a) {  // +128B (4 k-rows)
  i32x2 d;
  asm volatile("ds_read_b64_tr_b16 %0, %1 offset:128" : "=v"(d) : "v"(a));
  return d;
}
static __device__ __forceinline__ unsigned pk2(float lo, float hi2) {
  unsigned short a = __builtin_bit_cast(unsigned short, (bf16_t)lo);
  unsigned short b = __builtin_bit_cast(unsigned short, (bf16_t)hi2);
  return (unsigned)a | ((unsigned)b << 16);
}

#define WAITV4 { asm volatile("s_waitcnt vmcnt(4)" ::: "memory"); __builtin_amdgcn_sched_barrier(0); }
#define WAITV0 { asm volatile("s_waitcnt vmcnt(0)" ::: "memory"); __builtin_amdgcn_sched_barrier(0); }
#define BAR    { __builtin_amdgcn_s_barrier(); __builtin_amdgcn_sched_barrier(0); }
#define WAITL0 { asm volatile("s_waitcnt lgkmcnt(0)" ::: "memory"); __builtin_amdgcn_sched_barrier(0); }

// ---------------- fused fp32 -> bf16 conversion (x + 4 weights, one launch) ----------------
// grid (1024, 8): every segment is 1M f32 elems = 256K float4.
__global__ __launch_bounds__(256) void cvt_all(const float* __restrict__ x,
                                               const float* __restrict__ w0,
                                               const float* __restrict__ w1,
                                               const float* __restrict__ w2,
                                               const float* __restrict__ w3,
                                               bf16_t* __restrict__ out) {
  const int y = blockIdx.y;
  const float* in = (y < 4) ? (x + (size_t)y * 1048576)
                            : (y == 4 ? w0 : y == 5 ? w1 : y == 6 ? w2 : w3);
  bf16_t* o = out + (size_t)y * 1048576;
  int i = blockIdx.x * 256 + threadIdx.x;
  float4 f = reinterpret_cast<const float4*>(in)[i];
  bf16x4 v;
  v[0] = (bf16_t)f.x; v[1] = (bf16_t)f.y; v[2] = (bf16_t)f.z; v[3] = (bf16_t)f.w;
  reinterpret_cast<bf16x4*>(o)[i] = v;
}

// ---------------- NT GEMM: C = A * B^T ----------------
// BK=64, double-buffered, counted pipeline: per iter
//   {WAITV0; BAR; stage(ks+1); ds_read frags; WAITL0; 32 MFMA}.
// stage(ks+1) is issued after BAR_ks -> race-free vs other waves' reads of the
// buffer it overwrites (their reads retired at WAITL0 before reaching BAR_ks).
// The vmcnt(0) drain has a full compute phase (~500cyc) to hide L2 latency.
// LDS 64KB -> 2 blocks/CU.
template <bool STORE_F32, bool QSCALE>
__global__ __launch_bounds__(256) void gemm_nt(const bf16_t* __restrict__ A,
                                               const bf16_t* __restrict__ Bm,
                                               void* __restrict__ Cv,
                                               int M, int N, int K) {
  __shared__ __align__(16) bf16_t As[2][128 * 64];
  __shared__ __align__(16) bf16_t Bs[2][128 * 64];
  const int tid = threadIdx.x, lane = tid & 63, wave = tid >> 6;
  const int l15 = lane & 15;
  const int brow = blockIdx.y * 128, bcol = blockIdx.x * 128;
  const int row0 = (wave >> 1) * 64, col0 = (wave & 1) * 64;
  const float cscale = (QSCALE && bcol < 1024) ? 0.18033688011112042f : 1.0f;

  f32x4 acc[4][4];
#pragma unroll
  for (int m = 0; m < 4; ++m)
#pragma unroll
    for (int n = 0; n < 4; ++n) acc[m][n] = f32x4{0.f, 0.f, 0.f, 0.f};

  const int nst = K >> 6;  // K/64 steps (16 at K=1024)
  const int sr = lane >> 3;          // 0..7 row-in-8
  const int sc8 = (lane & 7) * 8;    // col granule
  // stage one 128x64 tile of each matrix: 4 rounds/matrix, wave w covers rows 8w+32i
  auto stage = [&](int bi, int ks) {
    const int k0 = ks * 64;
#pragma unroll
    for (int i = 0; i < 4; ++i)
      gld16(A + (size_t)(brow + 32 * i + 8 * wave + sr) * K + k0 + sc8,
            &As[bi][(32 * i + 8 * wave) * 64]);
#pragma unroll
    for (int i = 0; i < 4; ++i)
      gld16(Bm + (size_t)(bcol + 32 * i + 8 * wave + sr) * K + k0 + sc8,
            &Bs[bi][(32 * i + 8 * wave) * 64]);
  };

  stage(0, 0);

#pragma unroll 1
  for (int ks = 0; ks < nst; ++ks) {
    WAITV0;  // drain stage(ks); had a full compute phase to land (except iter 0)
    BAR;
    if (ks + 1 < nst) stage((ks + 1) & 1, ks + 1);

    const bf16_t* Ab = &As[ks & 1][0];
    const bf16_t* Bb = &Bs[ks & 1][0];
    bf16x8 af[4][2], bfr[4][2];
#pragma unroll
    for (int kk = 0; kk < 2; ++kk) {
      const int ko = kk * 32 + (lane >> 4) * 8;
#pragma unroll
      for (int m = 0; m < 4; ++m)
        af[m][kk] = *(const bf16x8*)&Ab[(row0 + 16 * m + l15) * 64 + ko];
#pragma unroll
      for (int n = 0; n < 4; ++n)
        bfr[n][kk] = *(const bf16x8*)&Bb[(col0 + 16 * n + l15) * 64 + ko];
    }
    WAITL0;
#pragma unroll
    for (int kk = 0; kk < 2; ++kk)
#pragma unroll
      for (int m = 0; m < 4; ++m)
#pragma unroll
        for (int n = 0; n < 4; ++n)
          acc[m][n] = mfma16(af[m][kk], bfr[n][kk], acc[m][n]);
  }

  const int crow = brow + row0 + (lane >> 4) * 4;
  const int ccol = bcol + col0 + l15;
#pragma unroll
  for (int m = 0; m < 4; ++m)
#pragma unroll
    for (int n = 0; n < 4; ++n)
#pragma unroll
      for (int r = 0; r < 4; ++r) {
        size_t idx = (size_t)(crow + 16 * m + r) * N + (ccol + 16 * n);
        float v = acc[m][n][r] * cscale;
        if (STORE_F32) reinterpret_cast<float*>(Cv)[idx] = v;
        else reinterpret_cast<bf16_t*>(Cv)[idx] = (bf16_t)v;
      }
}

// ---------------- causal flash attention (exact R6 revert: best measured 73.4us) ----------------
// Block = 256 thr (4 waves), grid (32 bh, 8 p) -> 256 blocks, 1/CU, all equal-length:
//   phase A: wave w owns chunk 4p+w    (block stages 2p+2 tiles)
//   phase B: wave w owns chunk 63-4p-w (block stages 32-2p tiles)
// Every wave = 33 compute tiles; every block = 34 staged tiles -> zero tail imbalance.
// Triple-buffered K/V, raw s_barrier + counted vmcnt(4): prefetch never drains.
#define CROW(r) ((((r) & 3) + 8 * ((r) >> 2)) + 4 * hi)

__global__ __launch_bounds__(256, 1) void attn_fwd(const bf16_t* __restrict__ qkv,
                                                   bf16_t* __restrict__ ctx) {
  __shared__ __align__(128) bf16_t KV[3][2][64 * 64];  // [buf][K|V][4096] = 48 KB
  const int tid = threadIdx.x;
  const int lane = tid & 63;
  const int wv = tid >> 6;
  const int bh = blockIdx.x, p = blockIdx.y;
  const int b = bh >> 4, h = bh & 15;
  const bf16_t* Qg = qkv + (size_t)b * T_ * RS_ + h * DH_;
  const bf16_t* Kg = Qg + 1024;
  const bf16_t* Vg = Qg + 2048;
  bf16_t* Cg = ctx + (size_t)b * T_ * D_ + h * DH_;

  const int hi = lane >> 5;
  const int l31 = lane & 31;
  const int l15 = lane & 15;

  auto stage = [&](int bi, int kt) {
    bf16_t* Kb = &KV[bi][0][0];
    bf16_t* Vb = &KV[bi][1][0];
#pragma unroll
    for (int i = 0; i < 2; ++i) {
      int c2 = i * 256 + tid;
      int r = c2 >> 3, g8 = (c2 & 7) ^ (r & 7);
      gld16(Kg + (size_t)(kt * 64 + r) * RS_ + g8 * 8, Kb + i * 2048 + wv * 512);
    }
#pragma unroll
    for (int i = 0; i < 2; ++i) {
      int c2 = i * 256 + tid;
      int pn = c2 >> 7, k = (c2 >> 1) & 63, half = c2 & 1;
      gld16(Vg + (size_t)(kt * 64 + k) * RS_ + pn * 16 + half * 8, Vb + i * 2048 + wv * 512);
    }
  };

#pragma unroll 1
  for (int phase = 0; phase < 2; ++phase) {
    const int c = phase ? (63 - 4 * p - wv) : (4 * p + wv);
    const int q0 = c * 32;
    const int mynkt = (c >> 1) + 1;
    const int maxnkt = phase ? (32 - 2 * p) : (2 * p + 2);

    BAR;  // previous phase's LDS reads fully retired before re-staging
    stage(0, 0);
    stage(1, 1);

    bf16x8 qf[4];
#pragma unroll
    for (int d = 0; d < 4; ++d)
      qf[d] = *(const bf16x8*)&Qg[(size_t)(q0 + l31) * RS_ + d * 16 + hi * 8];

    f32x16 o[2];
#pragma unroll
    for (int n = 0; n < 2; ++n)
#pragma unroll
      for (int r = 0; r < 16; ++r) o[n][r] = 0.f;
    float mrow = -1e30f, lsum = 0.f;

#pragma unroll 1
    for (int kt = 0; kt < maxnkt; ++kt) {
      if (kt + 1 < maxnkt) { WAITV4 } else { WAITV0 }
      BAR;
      if (kt + 2 < maxnkt) stage((kt + 2) % 3, kt + 2);

      if (kt < mynkt) {
        const bf16_t* Kb = &KV[kt % 3][0][0];
        bf16x8 kf[2][4];
#pragma unroll
        for (int t = 0; t < 2; ++t)
#pragma unroll
          for (int d = 0; d < 4; ++d) {
            int row = 32 * t + l31;
            int col = ((d * 2 + hi) ^ (row & 7)) * 8;
            kf[t][d] = *(const bf16x8*)&Kb[row * 64 + col];
          }
        bf16x8 vf[2][4];
        {
          unsigned vb = lds_addr(&KV[kt % 3][1][0]);
#pragma unroll
          for (int n2 = 0; n2 < 2; ++n2)
#pragma unroll
            for (int ks = 0; ks < 4; ++ks) {
              int pn = 2 * n2 + (l31 >> 4);
              int k0 = ks * 16 + hi * 8;
              unsigned a = vb + pn * 2048 + k0 * 32 + l15 * 8;
              i32x2 lo = tr64(a);
              i32x2 hi4 = tr64o(a);
              union { unsigned u[4]; bf16x8 v; } uu;
              uu.u[0] = (unsigned)lo[0]; uu.u[1] = (unsigned)lo[1];
              uu.u[2] = (unsigned)hi4[0]; uu.u[3] = (unsigned)hi4[1];
              vf[n2][ks] = uu.v;
            }
        }
        WAITL0;

        f32x16 st[2];
#pragma unroll
        for (int t = 0; t < 2; ++t) {
#pragma unroll
          for (int r = 0; r < 16; ++r) st[t][r] = 0.f;
#pragma unroll
          for (int d = 0; d < 4; ++d) st[t] = mfma32(kf[t][d], qf[d], st[t]);
        }
        if (kt == mynkt - 1) {
#pragma unroll
          for (int t = 0; t < 2; ++t)
#pragma unroll
            for (int r = 0; r < 16; ++r)
              if (kt * 64 + 32 * t + CROW(r) > q0 + l31) st[t][r] = -1e30f;
        }
        float pm = -1e30f;
#pragma unroll
        for (int t = 0; t < 2; ++t)
#pragma unroll
          for (int r = 0; r < 16; ++r) pm = fmaxf(pm, st[t][r]);
        pm = fmaxf(pm, __shfl_xor(pm, 32));
        if (!__all(pm - mrow <= 11.0f)) {
          float mn = fmaxf(mrow, pm);
          float scl = exp2f(mrow - mn);
          mrow = mn;
          lsum *= scl;
#pragma unroll
          for (int r = 0; r < 16; ++r) {
            float sr = __shfl(scl, CROW(r));
            o[0][r] *= sr;
            o[1][r] *= sr;
          }
        }
        float ps = 0.f;
#pragma unroll
        for (int t = 0; t < 2; ++t)
#pragma unroll
          for (int r = 0; r < 16; ++r) {
            float e = exp2f(st[t][r] - mrow);
            st[t][r] = e;
            ps += e;
          }
        ps += __shfl_xor(ps, 32);
        lsum += ps;
        unsigned pk[2][8];
#pragma unroll
        for (int t = 0; t < 2; ++t)
#pragma unroll
          for (int j = 0; j < 8; ++j) pk[t][j] = pk2(st[t][2 * j], st[t][2 * j + 1]);
#pragma unroll
        for (int ks = 0; ks < 4; ++ks) {
          const int t = ks >> 1, rb = (ks & 1) * 4;
          unsigned s0 = hi ? pk[t][rb] : pk[t][rb + 2];
          unsigned s1 = hi ? pk[t][rb + 1] : pk[t][rb + 3];
          unsigned r0 = (unsigned)__shfl_xor((int)s0, 32);
          unsigned r1 = (unsigned)__shfl_xor((int)s1, 32);
          union { unsigned u[4]; bf16x8 v; } w;
          if (hi == 0) {
            w.u[0] = pk[t][rb]; w.u[1] = pk[t][rb + 1]; w.u[2] = r0; w.u[3] = r1;
          } else {
            w.u[0] = r0; w.u[1] = r1; w.u[2] = pk[t][rb + 2]; w.u[3] = pk[t][rb + 3];
          }
          o[0] = mfma32(w.v, vf[0][ks], o[0]);
          o[1] = mfma32(w.v, vf[1][ks], o[1]);
        }
      }  // compute guard
    }  // kt

#pragma unroll
    for (int r = 0; r < 16; ++r) {
      float li = __shfl(lsum, CROW(r));
      float inv = 1.0f / li;
      int qrow = q0 + CROW(r);
#pragma unroll
      for (int n2 = 0; n2 < 2; ++n2)
        Cg[(size_t)qrow * D_ + n2 * 32 + l31] = (bf16_t)(o[n2][r] * inv);
    }
  }  // phase
}

// ---------------- launch ----------------
extern "C" void kernel_launch(void* const* d_in, const int* in_sizes, int n_in,
                              void* d_out, int out_size, void* d_ws, size_t ws_size,
                              hipStream_t stream) {
  const float* x   = (const float*)d_in[0];
  const float* w_q = (const float*)d_in[1];
  const float* w_k = (const float*)d_in[2];
  const float* w_v = (const float*)d_in[3];
  const float* w_o = (const float*)d_in[4];

  const int M = B_ * T_;              // 4096
  const size_t XN = (size_t)M * D_;   // 4M
  const size_t WN = (size_t)D_ * D_;  // 1M

  bf16_t* ws = (bf16_t*)d_ws;
  bf16_t* xb   = ws;            // 4M
  bf16_t* wqb  = xb + XN;       // 3M (q,k,v) + 1M (o) contiguous
  bf16_t* wob  = wqb + 3 * WN;
  bf16_t* qkv  = wob + WN;      // [4096][3072] = 12M
  bf16_t* ctx  = qkv + (size_t)M * RS_;  // 4M

  // fused conversion: x (4 segments) + 4 weights, all 1M-elem segments
  cvt_all<<<dim3(1024, 8), 256, 0, stream>>>(x, w_q, w_k, w_v, w_o, ws);

  // fused QKV GEMM: B = [w_q; w_k; w_v] (3072 x 1024), q-part pre-scaled (exp2 domain)
  gemm_nt<false, true><<<dim3(RS_ / 128, M / 128), 256, 0, stream>>>(xb, wqb, qkv, M, RS_, D_);

  attn_fwd<<<dim3(B_ * H_, 8), 256, 0, stream>>>(qkv, ctx);

  gemm_nt<true, false><<<dim3(D_ / 128, M / 128), 256, 0, stream>>>(ctx, wob, d_out, M, D_, D_);
}

// Round 12
// 133.881 us; speedup vs baseline: 1.2491x; 1.1488x over previous
//
#include <hip/hip_runtime.h>
#include <hip/hip_bf16.h>

typedef __bf16 bf16_t;
typedef __attribute__((ext_vector_type(8))) __bf16 bf16x8;
typedef __attribute__((ext_vector_type(4))) __bf16 bf16x4;
typedef __attribute__((ext_vector_type(4))) float f32x4;
typedef __attribute__((ext_vector_type(16))) float f32x16;
typedef __attribute__((ext_vector_type(2))) int i32x2;

#define B_ 2
#define T_ 2048
#define D_ 1024
#define H_ 16
#define DH_ 64
#define RS_ 3072  // fused qkv row stride

static __device__ __forceinline__ f32x4 mfma16(bf16x8 a, bf16x8 b, f32x4 c) {
  return __builtin_amdgcn_mfma_f32_16x16x32_bf16(a, b, c, 0, 0, 0);
}
static __device__ __forceinline__ f32x16 mfma32(bf16x8 a, bf16x8 b, f32x16 c) {
  return __builtin_amdgcn_mfma_f32_32x32x16_bf16(a, b, c, 0, 0, 0);
}
static __device__ __forceinline__ void gld16(const bf16_t* g, bf16_t* l) {
  __builtin_amdgcn_global_load_lds(
      (const __attribute__((address_space(1))) unsigned int*)g,
      (__attribute__((address_space(3))) unsigned int*)l, 16, 0, 0);
}
static __device__ __forceinline__ unsigned lds_addr(const bf16_t* p) {
  return (unsigned)(uintptr_t)(const __attribute__((address_space(3))) bf16_t*)p;
}
static __device__ __forceinline__ i32x2 tr64(unsigned a) {
  i32x2 d;
  asm volatile("ds_read_b64_tr_b16 %0, %1" : "=v"(d) : "v"(a));
  return d;
}
static __device__ __forceinline__ i32x2 tr64o(unsigned a) {  // +128B (4 k-rows)
  i32x2 d;
  asm volatile("ds_read_b64_tr_b16 %0, %1 offset:128" : "=v"(d) : "v"(a));
  return d;
}
static __device__ __forceinline__ unsigned pk2(float lo, float hi2) {
  unsigned short a = __builtin_bit_cast(unsigned short, (bf16_t)lo);
  unsigned short b = __builtin_bit_cast(unsigned short, (bf16_t)hi2);
  return (unsigned)a | ((unsigned)b << 16);
}

#define WAITV3 { asm volatile("s_waitcnt vmcnt(3)" ::: "memory"); __builtin_amdgcn_sched_barrier(0); }
#define WAITV4 { asm volatile("s_waitcnt vmcnt(4)" ::: "memory"); __builtin_amdgcn_sched_barrier(0); }
#define WAITV0 { asm volatile("s_waitcnt vmcnt(0)" ::: "memory"); __builtin_amdgcn_sched_barrier(0); }
#define BAR    { __builtin_amdgcn_s_barrier(); __builtin_amdgcn_sched_barrier(0); }
#define WAITL0 { asm volatile("s_waitcnt lgkmcnt(0)" ::: "memory"); __builtin_amdgcn_sched_barrier(0); }

// ---------------- fused fp32 -> bf16 conversion (x + 4 weights, one launch) ----------------
__global__ __launch_bounds__(256) void cvt_all(const float* __restrict__ x,
                                               const float* __restrict__ w0,
                                               const float* __restrict__ w1,
                                               const float* __restrict__ w2,
                                               const float* __restrict__ w3,
                                               bf16_t* __restrict__ out) {
  const int y = blockIdx.y;
  const float* in = (y < 4) ? (x + (size_t)y * 1048576)
                            : (y == 4 ? w0 : y == 5 ? w1 : y == 6 ? w2 : w3);
  bf16_t* o = out + (size_t)y * 1048576;
  int i = blockIdx.x * 256 + threadIdx.x;
  float4 f = reinterpret_cast<const float4*>(in)[i];
  bf16x4 v;
  v[0] = (bf16_t)f.x; v[1] = (bf16_t)f.y; v[2] = (bf16_t)f.z; v[3] = (bf16_t)f.w;
  reinterpret_cast<bf16x4*>(o)[i] = v;
}

// ---------------- NT GEMM 128x128 (exact R7: triple-buffer BK=32, vmcnt(4)) ----------------
template <bool STORE_F32, bool QSCALE>
__global__ __launch_bounds__(256) void gemm_nt(const bf16_t* __restrict__ A,
                                               const bf16_t* __restrict__ Bm,
                                               void* __restrict__ Cv,
                                               int M, int N, int K) {
  __shared__ __align__(16) bf16_t As[3][128 * 32];
  __shared__ __align__(16) bf16_t Bs[3][128 * 32];
  const int tid = threadIdx.x, lane = tid & 63, wave = tid >> 6;
  const int l15 = lane & 15;
  const int brow = blockIdx.y * 128, bcol = blockIdx.x * 128;
  const int row0 = (wave >> 1) * 64, col0 = (wave & 1) * 64;
  const float cscale = (QSCALE && bcol < 1024) ? 0.18033688011112042f : 1.0f;

  f32x4 acc[4][4];
#pragma unroll
  for (int m = 0; m < 4; ++m)
#pragma unroll
    for (int n = 0; n < 4; ++n) acc[m][n] = f32x4{0.f, 0.f, 0.f, 0.f};

  const int nst = K >> 5;
  const int srow = tid >> 2;
  const int sc8 = (tid & 3) * 8;
  auto stage = [&](int bi, int ks) {
    const int k0 = ks * 32;
#pragma unroll
    for (int i = 0; i < 2; ++i)
      gld16(A + (size_t)(brow + 64 * i + srow) * K + k0 + sc8,
            &As[bi][2048 * i + 512 * wave]);
#pragma unroll
    for (int i = 0; i < 2; ++i)
      gld16(Bm + (size_t)(bcol + 64 * i + srow) * K + k0 + sc8,
            &Bs[bi][2048 * i + 512 * wave]);
  };

  stage(0, 0);
  stage(1, 1);

#pragma unroll 1
  for (int ks = 0; ks < nst; ++ks) {
    if (ks + 1 < nst) { WAITV4 } else { WAITV0 }
    BAR;
    if (ks + 2 < nst) stage((ks + 2) % 3, ks + 2);

    const bf16_t* Ab = &As[ks % 3][0];
    const bf16_t* Bb = &Bs[ks % 3][0];
    const int ko = (lane >> 4) * 8;
    bf16x8 af[4], bfr[4];
#pragma unroll
    for (int m = 0; m < 4; ++m)
      af[m] = *(const bf16x8*)&Ab[(row0 + 16 * m + l15) * 32 + ko];
#pragma unroll
    for (int n = 0; n < 4; ++n)
      bfr[n] = *(const bf16x8*)&Bb[(col0 + 16 * n + l15) * 32 + ko];
    WAITL0;
#pragma unroll
    for (int m = 0; m < 4; ++m)
#pragma unroll
      for (int n = 0; n < 4; ++n) acc[m][n] = mfma16(af[m], bfr[n], acc[m][n]);
  }

  const int crow = brow + row0 + (lane >> 4) * 4;
  const int ccol = bcol + col0 + l15;
#pragma unroll
  for (int m = 0; m < 4; ++m)
#pragma unroll
    for (int n = 0; n < 4; ++n)
#pragma unroll
      for (int r = 0; r < 4; ++r) {
        size_t idx = (size_t)(crow + 16 * m + r) * N + (ccol + 16 * n);
        float v = acc[m][n][r] * cscale;
        if (STORE_F32) reinterpret_cast<float*>(Cv)[idx] = v;
        else reinterpret_cast<bf16_t*>(Cv)[idx] = (bf16_t)v;
      }
}

// ---------------- NT GEMM 64x128 (out-proj: 512 blocks -> 2 blocks/CU) ----------------
// Same triple-buffer counted pipeline; stage = 3 loads/thread -> vmcnt(3).
__global__ __launch_bounds__(256) void gemm_nt64(const bf16_t* __restrict__ A,
                                                 const bf16_t* __restrict__ Bm,
                                                 float* __restrict__ Cv,
                                                 int M, int N, int K) {
  __shared__ __align__(16) bf16_t As[3][64 * 32];
  __shared__ __align__(16) bf16_t Bs[3][128 * 32];
  const int tid = threadIdx.x, lane = tid & 63, wave = tid >> 6;
  const int l15 = lane & 15;
  const int brow = blockIdx.y * 64, bcol = blockIdx.x * 128;
  const int row0 = (wave >> 1) * 32, col0 = (wave & 1) * 64;

  f32x4 acc[2][4];
#pragma unroll
  for (int m = 0; m < 2; ++m)
#pragma unroll
    for (int n = 0; n < 4; ++n) acc[m][n] = f32x4{0.f, 0.f, 0.f, 0.f};

  const int nst = K >> 5;  // 32 steps at K=1024
  const int sr = lane >> 2;        // 0..15
  const int sc8 = (lane & 3) * 8;  // col granule
  auto stage = [&](int bi, int ks) {
    const int k0 = ks * 32;
    gld16(A + (size_t)(brow + 16 * wave + sr) * K + k0 + sc8, &As[bi][512 * wave]);
#pragma unroll
    for (int i = 0; i < 2; ++i)
      gld16(Bm + (size_t)(bcol + 64 * i + 16 * wave + sr) * K + k0 + sc8,
            &Bs[bi][2048 * i + 512 * wave]);
  };

  stage(0, 0);
  stage(1, 1);

#pragma unroll 1
  for (int ks = 0; ks < nst; ++ks) {
    if (ks + 1 < nst) { WAITV3 } else { WAITV0 }
    BAR;
    if (ks + 2 < nst) stage((ks + 2) % 3, ks + 2);

    const bf16_t* Ab = &As[ks % 3][0];
    const bf16_t* Bb = &Bs[ks % 3][0];
    const int ko = (lane >> 4) * 8;
    bf16x8 af[2], bfr[4];
#pragma unroll
    for (int m = 0; m < 2; ++m)
      af[m] = *(const bf16x8*)&Ab[(row0 + 16 * m + l15) * 32 + ko];
#pragma unroll
    for (int n = 0; n < 4; ++n)
      bfr[n] = *(const bf16x8*)&Bb[(col0 + 16 * n + l15) * 32 + ko];
    WAITL0;
#pragma unroll
    for (int m = 0; m < 2; ++m)
#pragma unroll
      for (int n = 0; n < 4; ++n) acc[m][n] = mfma16(af[m], bfr[n], acc[m][n]);
  }

  const int crow = brow + row0 + (lane >> 4) * 4;
  const int ccol = bcol + col0 + l15;
#pragma unroll
  for (int m = 0; m < 2; ++m)
#pragma unroll
    for (int n = 0; n < 4; ++n)
#pragma unroll
      for (int r = 0; r < 4; ++r)
        Cv[(size_t)(crow + 16 * m + r) * N + (ccol + 16 * n)] = acc[m][n][r];
}

// ---------------- causal flash attention (R6 structure: best measured 73.4us) ----------------
#define CROW(r) ((((r) & 3) + 8 * ((r) >> 2)) + 4 * hi)

__global__ __launch_bounds__(256, 1) void attn_fwd(const bf16_t* __restrict__ qkv,
                                                   bf16_t* __restrict__ ctx) {
  __shared__ __align__(128) bf16_t KV[3][2][64 * 64];  // [buf][K|V][4096] = 48 KB
  const int tid = threadIdx.x;
  const int lane = tid & 63;
  const int wv = tid >> 6;
  const int bh = blockIdx.x, p = blockIdx.y;
  const int b = bh >> 4, h = bh & 15;
  const bf16_t* Qg = qkv + (size_t)b * T_ * RS_ + h * DH_;
  const bf16_t* Kg = Qg + 1024;
  const bf16_t* Vg = Qg + 2048;
  bf16_t* Cg = ctx + (size_t)b * T_ * D_ + h * DH_;

  const int hi = lane >> 5;
  const int l31 = lane & 31;
  const int l15 = lane & 15;

  auto stage = [&](int bi, int kt) {
    bf16_t* Kb = &KV[bi][0][0];
    bf16_t* Vb = &KV[bi][1][0];
#pragma unroll
    for (int i = 0; i < 2; ++i) {
      int c2 = i * 256 + tid;
      int r = c2 >> 3, g8 = (c2 & 7) ^ (r & 7);
      gld16(Kg + (size_t)(kt * 64 + r) * RS_ + g8 * 8, Kb + i * 2048 + wv * 512);
    }
#pragma unroll
    for (int i = 0; i < 2; ++i) {
      int c2 = i * 256 + tid;
      int pn = c2 >> 7, k = (c2 >> 1) & 63, half = c2 & 1;
      gld16(Vg + (size_t)(kt * 64 + k) * RS_ + pn * 16 + half * 8, Vb + i * 2048 + wv * 512);
    }
  };

#pragma unroll 1
  for (int phase = 0; phase < 2; ++phase) {
    const int c = phase ? (63 - 4 * p - wv) : (4 * p + wv);
    const int q0 = c * 32;
    const int mynkt = (c >> 1) + 1;
    const int maxnkt = phase ? (32 - 2 * p) : (2 * p + 2);

    BAR;
    stage(0, 0);
    stage(1, 1);

    bf16x8 qf[4];
#pragma unroll
    for (int d = 0; d < 4; ++d)
      qf[d] = *(const bf16x8*)&Qg[(size_t)(q0 + l31) * RS_ + d * 16 + hi * 8];

    f32x16 o[2];
#pragma unroll
    for (int n = 0; n < 2; ++n)
#pragma unroll
      for (int r = 0; r < 16; ++r) o[n][r] = 0.f;
    float mrow = -1e30f, lsum = 0.f;

#pragma unroll 1
    for (int kt = 0; kt < maxnkt; ++kt) {
      if (kt + 1 < maxnkt) { WAITV4 } else { WAITV0 }
      BAR;
      if (kt + 2 < maxnkt) stage((kt + 2) % 3, kt + 2);

      if (kt < mynkt) {
        const bf16_t* Kb = &KV[kt % 3][0][0];
        bf16x8 kf[2][4];
#pragma unroll
        for (int t = 0; t < 2; ++t)
#pragma unroll
          for (int d = 0; d < 4; ++d) {
            int row = 32 * t + l31;
            int col = ((d * 2 + hi) ^ (row & 7)) * 8;
            kf[t][d] = *(const bf16x8*)&Kb[row * 64 + col];
          }
        bf16x8 vf[2][4];
        {
          unsigned vb = lds_addr(&KV[kt % 3][1][0]);
#pragma unroll
          for (int n2 = 0; n2 < 2; ++n2)
#pragma unroll
            for (int ks = 0; ks < 4; ++ks) {
              int pn = 2 * n2 + (l31 >> 4);
              int k0 = ks * 16 + hi * 8;
              unsigned a = vb + pn * 2048 + k0 * 32 + l15 * 8;
              i32x2 lo = tr64(a);
              i32x2 hi4 = tr64o(a);
              union { unsigned u[4]; bf16x8 v; } uu;
              uu.u[0] = (unsigned)lo[0]; uu.u[1] = (unsigned)lo[1];
              uu.u[2] = (unsigned)hi4[0]; uu.u[3] = (unsigned)hi4[1];
              vf[n2][ks] = uu.v;
            }
        }
        WAITL0;

        f32x16 st[2];
#pragma unroll
        for (int t = 0; t < 2; ++t) {
#pragma unroll
          for (int r = 0; r < 16; ++r) st[t][r] = 0.f;
#pragma unroll
          for (int d = 0; d < 4; ++d) st[t] = mfma32(kf[t][d], qf[d], st[t]);
        }
        if (kt == mynkt - 1) {
#pragma unroll
          for (int t = 0; t < 2; ++t)
#pragma unroll
            for (int r = 0; r < 16; ++r)
              if (kt * 64 + 32 * t + CROW(r) > q0 + l31) st[t][r] = -1e30f;
        }
        float pm = -1e30f;
#pragma unroll
        for (int t = 0; t < 2; ++t)
#pragma unroll
          for (int r = 0; r < 16; ++r) pm = fmaxf(pm, st[t][r]);
        pm = fmaxf(pm, __shfl_xor(pm, 32));
        if (!__all(pm - mrow <= 11.0f)) {
          float mn = fmaxf(mrow, pm);
          float scl = exp2f(mrow - mn);
          mrow = mn;
          lsum *= scl;
#pragma unroll
          for (int r = 0; r < 16; ++r) {
            float sr = __shfl(scl, CROW(r));
            o[0][r] *= sr;
            o[1][r] *= sr;
          }
        }
        float ps = 0.f;
#pragma unroll
        for (int t = 0; t < 2; ++t)
#pragma unroll
          for (int r = 0; r < 16; ++r) {
            float e = exp2f(st[t][r] - mrow);
            st[t][r] = e;
            ps += e;
          }
        ps += __shfl_xor(ps, 32);
        lsum += ps;
        unsigned pk[2][8];
#pragma unroll
        for (int t = 0; t < 2; ++t)
#pragma unroll
          for (int j = 0; j < 8; ++j) pk[t][j] = pk2(st[t][2 * j], st[t][2 * j + 1]);
#pragma unroll
        for (int ks = 0; ks < 4; ++ks) {
          const int t = ks >> 1, rb = (ks & 1) * 4;
          unsigned s0 = hi ? pk[t][rb] : pk[t][rb + 2];
          unsigned s1 = hi ? pk[t][rb + 1] : pk[t][rb + 3];
          unsigned r0 = (unsigned)__shfl_xor((int)s0, 32);
          unsigned r1 = (unsigned)__shfl_xor((int)s1, 32);
          union { unsigned u[4]; bf16x8 v; } w;
          if (hi == 0) {
            w.u[0] = pk[t][rb]; w.u[1] = pk[t][rb + 1]; w.u[2] = r0; w.u[3] = r1;
          } else {
            w.u[0] = r0; w.u[1] = r1; w.u[2] = pk[t][rb + 2]; w.u[3] = pk[t][rb + 3];
          }
          o[0] = mfma32(w.v, vf[0][ks], o[0]);
          o[1] = mfma32(w.v, vf[1][ks], o[1]);
        }
      }  // compute guard
    }  // kt

#pragma unroll
    for (int r = 0; r < 16; ++r) {
      float li = __shfl(lsum, CROW(r));
      float inv = 1.0f / li;
      int qrow = q0 + CROW(r);
#pragma unroll
      for (int n2 = 0; n2 < 2; ++n2)
        Cg[(size_t)qrow * D_ + n2 * 32 + l31] = (bf16_t)(o[n2][r] * inv);
    }
  }  // phase
}

// ---------------- launch ----------------
extern "C" void kernel_launch(void* const* d_in, const int* in_sizes, int n_in,
                              void* d_out, int out_size, void* d_ws, size_t ws_size,
                              hipStream_t stream) {
  const float* x   = (const float*)d_in[0];
  const float* w_q = (const float*)d_in[1];
  const float* w_k = (const float*)d_in[2];
  const float* w_v = (const float*)d_in[3];
  const float* w_o = (const float*)d_in[4];

  const int M = B_ * T_;              // 4096
  const size_t XN = (size_t)M * D_;   // 4M
  const size_t WN = (size_t)D_ * D_;  // 1M

  bf16_t* ws = (bf16_t*)d_ws;
  bf16_t* xb   = ws;            // 4M
  bf16_t* wqb  = xb + XN;       // 3M (q,k,v) + 1M (o) contiguous
  bf16_t* wob  = wqb + 3 * WN;
  bf16_t* qkv  = wob + WN;      // [4096][3072] = 12M
  bf16_t* ctx  = qkv + (size_t)M * RS_;  // 4M

  cvt_all<<<dim3(1024, 8), 256, 0, stream>>>(x, w_q, w_k, w_v, w_o, ws);

  // fused QKV GEMM: B = [w_q; w_k; w_v] (3072 x 1024), q-part pre-scaled (exp2 domain)
  gemm_nt<false, true><<<dim3(RS_ / 128, M / 128), 256, 0, stream>>>(xb, wqb, qkv, M, RS_, D_);

  attn_fwd<<<dim3(B_ * H_, 8), 256, 0, stream>>>(qkv, ctx);

  // out-proj: 64x128 tile -> 512 blocks (2/CU) instead of 256 (1/CU)
  gemm_nt64<<<dim3(D_ / 128, M / 64), 256, 0, stream>>>(ctx, wob, (float*)d_out, M, D_, D_);
}